// Round 1
// baseline (235.459 us; speedup 1.0000x reference)
//
#include <hip/hip_runtime.h>

typedef __attribute__((ext_vector_type(8))) short short8;
typedef __attribute__((ext_vector_type(4))) float f32x4;

// Problem constants (B, D, E, S, H, Z) = (16384, 512, 16, 1, 256, 256)
constexpr int Bsz = 16384;
constexpr int Dd  = 512;
constexpr int Ee  = 16;
constexpr int Hh  = 256;
constexpr int Zz  = 256;
constexpr int BT  = 64;    // rows per block
constexpr int SMEM_MAIN = 65536 + 32768 + 64 * 16 * 4;  // hA + hidB + wc = 102400 B

__device__ __forceinline__ unsigned short f2bf(float f) {
    unsigned u = __float_as_uint(f);
    u += 0x7FFFu + ((u >> 16) & 1u);          // round-to-nearest-even
    return (unsigned short)(u >> 16);
}
__device__ __forceinline__ float bf2f(unsigned short s) {
    return __uint_as_float(((unsigned)s) << 16);
}

// Batched transpose + fp32->bf16: src [E][R][C] f32  ->  dst [E][C][R] bf16
// grid = E * (R/64) * (C/64), block = 256
__global__ void transpose_bf16(const float* __restrict__ src,
                               unsigned short* __restrict__ dst,
                               int R, int C) {
    __shared__ float tile[64][65];
    int tilesC = C >> 6, tilesR = R >> 6;
    int bid = blockIdx.x;
    int e  = bid / (tilesR * tilesC);
    int rm = bid % (tilesR * tilesC);
    int rt = rm / tilesC;
    int ct = rm % tilesC;
    int t  = threadIdx.x;
    int c  = t & 63;
    int r0 = t >> 6;
    const float* s = src + (size_t)e * R * C + (size_t)(rt * 64) * C + ct * 64;
    #pragma unroll
    for (int i = 0; i < 16; ++i) {
        int r = r0 + i * 4;
        tile[r][c] = s[(size_t)r * C + c];
    }
    __syncthreads();
    unsigned short* d = dst + (size_t)e * R * C + (size_t)(ct * 64) * R + rt * 64;
    #pragma unroll
    for (int i = 0; i < 16; ++i) {
        int r = r0 + i * 4;
        d[(size_t)r * R + c] = f2bf(tile[c][r]);
    }
}

// Fused SoftMoE: gating softmax + 16x (GEMM1 -> relu -> scale -> GEMM2) + combine
// grid = B/64 = 256 blocks, block = 512 threads (8 waves), dyn LDS = 102400 B
__global__ __launch_bounds__(512) void moe_fused(
    const float* __restrict__ hptr,            // [B][512] f32
    const float* __restrict__ phi,             // [512][16] f32
    const float* __restrict__ b1,              // [16][256] f32
    const float* __restrict__ b2,              // [16][256] f32
    const unsigned short* __restrict__ w1t,    // [16][256(h)][512(d)] bf16
    const unsigned short* __restrict__ w2t,    // [16][256(z)][256(h)] bf16
    float* __restrict__ out)                   // [B][256] f32
{
    extern __shared__ char smem[];
    char*  hA   = smem;                         // [64][512] bf16, slot^=(row&7) swizzle, 64KB
    char*  hidB = smem + 65536;                 // [64][256] bf16, swizzled, 32KB
    float* wc   = (float*)(smem + 65536 + 32768); // [64][16] gate weights -> softmax

    const int t    = threadIdx.x;
    const int lane = t & 63;
    const int wv   = t >> 6;          // wave 0..7, owns cols [wv*32, wv*32+32)
    const int l15  = lane & 15;
    const int lg   = lane >> 4;       // 0..3
    const int b0   = blockIdx.x * BT;

    // ---- stage h tile -> bf16 swizzled LDS (coalesced float4 reads) ----
    {
        const float4* hsrc = reinterpret_cast<const float4*>(hptr + (size_t)b0 * Dd);
        #pragma unroll
        for (int i = 0; i < 16; ++i) {
            int idx = t + i * 512;          // float4 index within tile (8192 total)
            int row = idx >> 7;             // 128 float4 per row
            int kc  = idx & 127;
            int k   = kc << 2;
            float4 v = hsrc[(size_t)row * 128 + kc];
            unsigned lo = (unsigned)f2bf(v.x) | ((unsigned)f2bf(v.y) << 16);
            unsigned hi = (unsigned)f2bf(v.z) | ((unsigned)f2bf(v.w) << 16);
            int byte = (row << 10) + (((k >> 3) ^ (row & 7)) << 4) + ((k & 7) << 1);
            *reinterpret_cast<uint2*>(hA + byte) = make_uint2(lo, hi);
        }
    }
    __syncthreads();

    // ---- gating: w[row][e] = h[row] . phi[:,e]  (each thread: 1 row, 2 experts) ----
    {
        int row = t >> 3;
        int e0  = t & 7;
        float a0 = 0.f, a1 = 0.f;
        for (int g = 0; g < 64; ++g) {
            short8 ch = *reinterpret_cast<const short8*>(
                hA + (row << 10) + ((g ^ (row & 7)) << 4));
            #pragma unroll
            for (int j = 0; j < 8; ++j) {
                float hv = bf2f((unsigned short)ch[j]);
                int k = g * 8 + j;
                a0 = fmaf(hv, phi[k * 16 + e0],     a0);
                a1 = fmaf(hv, phi[k * 16 + e0 + 8], a1);
            }
        }
        wc[row * 16 + e0]     = a0;
        wc[row * 16 + e0 + 8] = a1;
    }
    __syncthreads();
    if (t < 64) {
        float w[16];
        float m = -1e30f;
        #pragma unroll
        for (int e = 0; e < 16; ++e) { w[e] = wc[t * 16 + e]; m = fmaxf(m, w[e]); }
        float s = 0.f;
        #pragma unroll
        for (int e = 0; e < 16; ++e) { w[e] = __expf(w[e] - m); s += w[e]; }
        float inv = 1.f / s;
        #pragma unroll
        for (int e = 0; e < 16; ++e) wc[t * 16 + e] = w[e] * inv;
    }
    __syncthreads();

    const f32x4 zero4 = {0.f, 0.f, 0.f, 0.f};
    f32x4 outacc[4][2];
    #pragma unroll
    for (int m = 0; m < 4; ++m)
        #pragma unroll
        for (int n = 0; n < 2; ++n) outacc[m][n] = zero4;

    for (int e = 0; e < Ee; ++e) {
        // ---- GEMM1: hid = h @ W1[e]   (M=64, N=256 split 8 waves, K=512) ----
        f32x4 hacc[4][2];
        #pragma unroll
        for (int m = 0; m < 4; ++m)
            #pragma unroll
            for (int n = 0; n < 2; ++n) hacc[m][n] = zero4;

        const unsigned short* w1e = w1t + (size_t)e * Hh * Dd;
        #pragma unroll 2
        for (int ks = 0; ks < 8; ++ks) {
            #pragma unroll
            for (int kk = 0; kk < 2; ++kk) {
                int kl = ks * 64 + kk * 32 + lg * 8;
                short8 af[4];
                #pragma unroll
                for (int m = 0; m < 4; ++m) {
                    int row = m * 16 + l15;
                    af[m] = *reinterpret_cast<const short8*>(
                        hA + (row << 10) + (((kl >> 3) ^ (row & 7)) << 4));
                }
                #pragma unroll
                for (int n = 0; n < 2; ++n) {
                    int col = wv * 32 + n * 16 + l15;
                    short8 bfr = *reinterpret_cast<const short8*>(
                        w1e + (size_t)col * Dd + kl);
                    #pragma unroll
                    for (int m = 0; m < 4; ++m)
                        hacc[m][n] = __builtin_amdgcn_mfma_f32_16x16x32_bf16(
                            af[m], bfr, hacc[m][n], 0, 0, 0);
                }
            }
        }

        __syncthreads();   // previous expert's GEMM2 done reading hidB
        // ---- epilogue1: +b1, relu, * c[row,e], -> bf16 hidB ----
        #pragma unroll
        for (int n = 0; n < 2; ++n) {
            int col = wv * 32 + n * 16 + l15;
            float bias = b1[e * Hh + col];
            #pragma unroll
            for (int m = 0; m < 4; ++m) {
                #pragma unroll
                for (int j = 0; j < 4; ++j) {
                    int row = m * 16 + lg * 4 + j;      // C/D layout: col=l&15, row=(l>>4)*4+j
                    float v = hacc[m][n][j] + bias;
                    v = fmaxf(v, 0.f) * wc[row * 16 + e];
                    int byte = (row << 9) + (((col >> 3) ^ (row & 7)) << 4) + ((col & 7) << 1);
                    *reinterpret_cast<unsigned short*>(hidB + byte) = f2bf(v);
                }
            }
        }
        __syncthreads();

        // ---- GEMM2: out += (c*hid) @ W2[e]   (M=64, N=256, K=256) ----
        const unsigned short* w2e = w2t + (size_t)e * Zz * Hh;
        #pragma unroll 2
        for (int hs = 0; hs < 4; ++hs) {
            #pragma unroll
            for (int kk = 0; kk < 2; ++kk) {
                int kl = hs * 64 + kk * 32 + lg * 8;
                short8 af[4];
                #pragma unroll
                for (int m = 0; m < 4; ++m) {
                    int row = m * 16 + l15;
                    af[m] = *reinterpret_cast<const short8*>(
                        hidB + (row << 9) + (((kl >> 3) ^ (row & 7)) << 4));
                }
                #pragma unroll
                for (int n = 0; n < 2; ++n) {
                    int col = wv * 32 + n * 16 + l15;
                    short8 bfr = *reinterpret_cast<const short8*>(
                        w2e + (size_t)col * Hh + kl);
                    #pragma unroll
                    for (int m = 0; m < 4; ++m)
                        outacc[m][n] = __builtin_amdgcn_mfma_f32_16x16x32_bf16(
                            af[m], bfr, outacc[m][n], 0, 0, 0);
                }
            }
        }
    }

    // ---- final epilogue: out = outacc + sum_e c[row,e]*b2[e,:] ----
    #pragma unroll
    for (int n = 0; n < 2; ++n) {
        int col = wv * 32 + n * 16 + l15;
        #pragma unroll
        for (int m = 0; m < 4; ++m) {
            #pragma unroll
            for (int j = 0; j < 4; ++j) {
                int row = m * 16 + lg * 4 + j;
                float v = outacc[m][n][j];
                #pragma unroll
                for (int e = 0; e < 16; ++e)
                    v = fmaf(wc[row * 16 + e], b2[e * Zz + col], v);
                out[(size_t)(b0 + row) * Zz + col] = v;
            }
        }
    }
}

extern "C" void kernel_launch(void* const* d_in, const int* in_sizes, int n_in,
                              void* d_out, int out_size, void* d_ws, size_t ws_size,
                              hipStream_t stream) {
    const float* h   = (const float*)d_in[0];
    const float* phi = (const float*)d_in[1];
    const float* W1  = (const float*)d_in[2];
    const float* b1  = (const float*)d_in[3];
    const float* W2  = (const float*)d_in[4];
    const float* b2  = (const float*)d_in[5];
    float* out = (float*)d_out;

    unsigned short* w1t = (unsigned short*)d_ws;                      // 4 MB
    unsigned short* w2t = w1t + (size_t)Ee * Hh * Dd;                 // 2 MB

    (void)hipFuncSetAttribute((const void*)moe_fused,
                              hipFuncAttributeMaxDynamicSharedMemorySize, SMEM_MAIN);

    // weights -> bf16, transposed so MFMA B-fragments are K-contiguous
    transpose_bf16<<<Ee * (Dd / 64) * (Hh / 64), 256, 0, stream>>>(W1, w1t, Dd, Hh);
    transpose_bf16<<<Ee * (Hh / 64) * (Zz / 64), 256, 0, stream>>>(W2, w2t, Hh, Zz);

    moe_fused<<<Bsz / BT, 512, SMEM_MAIN, stream>>>(h, phi, b1, b2, w1t, w2t, out);
}

// Round 2
// 209.115 us; speedup vs baseline: 1.1260x; 1.1260x over previous
//
#include <hip/hip_runtime.h>

typedef __attribute__((ext_vector_type(8))) short short8;
typedef __attribute__((ext_vector_type(4))) float f32x4;

// Problem constants (B, D, E, S, H, Z) = (16384, 512, 16, 1, 256, 256)
constexpr int Bsz = 16384;
constexpr int Dd  = 512;
constexpr int Ee  = 16;
constexpr int Hh  = 256;
constexpr int Zz  = 256;
constexpr int BT  = 64;      // rows per block
constexpr int WCLD = 17;     // wc padded stride (bank-conflict-free)
constexpr int SMEM_MAIN = 65536 + 2 * 32768 + 64 * WCLD * 4;  // hA + hidB[2] + wc = 135424 B

__device__ __forceinline__ unsigned short f2bf(float f) {
    unsigned u = __float_as_uint(f);
    u += 0x7FFFu + ((u >> 16) & 1u);          // round-to-nearest-even
    return (unsigned short)(u >> 16);
}

// Batched transpose + fp32->bf16: src [E][R][C] f32  ->  dst [E][C][R] bf16
__global__ void transpose_bf16(const float* __restrict__ src,
                               unsigned short* __restrict__ dst,
                               int R, int C) {
    __shared__ float tile[64][65];
    int tilesC = C >> 6, tilesR = R >> 6;
    int bid = blockIdx.x;
    int e  = bid / (tilesR * tilesC);
    int rm = bid % (tilesR * tilesC);
    int rt = rm / tilesC;
    int ct = rm % tilesC;
    int t  = threadIdx.x;
    int c  = t & 63;
    int r0 = t >> 6;
    const float* s = src + (size_t)e * R * C + (size_t)(rt * 64) * C + ct * 64;
    #pragma unroll
    for (int i = 0; i < 16; ++i) {
        int r = r0 + i * 4;
        tile[r][c] = s[(size_t)r * C + c];
    }
    __syncthreads();
    unsigned short* d = dst + (size_t)e * R * C + (size_t)(ct * 64) * R + rt * 64;
    #pragma unroll
    for (int i = 0; i < 16; ++i) {
        int r = r0 + i * 4;
        d[(size_t)r * R + c] = f2bf(tile[c][r]);
    }
}

// Fused SoftMoE. grid = B/64 = 256 blocks, block = 512 threads (8 waves)
__global__ __launch_bounds__(512) void moe_fused(
    const float* __restrict__ hptr,            // [B][512] f32
    const float* __restrict__ phi,             // [512][16] f32
    const float* __restrict__ b1,              // [16][256] f32
    const float* __restrict__ b2,              // [16][256] f32
    const unsigned short* __restrict__ w1t,    // [16][256(h)][512(d)] bf16
    const unsigned short* __restrict__ w2t,    // [16][256(z)][256(h)] bf16
    float* __restrict__ out)                   // [B][256] f32
{
    extern __shared__ char smem[];
    char*  hA    = smem;                          // [64][512] bf16 swizzled, 64KB
    char*  hidB0 = smem + 65536;                  // [64][256] bf16 swizzled, 32KB
    char*  hidB1 = smem + 65536 + 32768;          // 32KB
    float* wc    = (float*)(smem + 131072);       // [64][17] gate softmax

    const int t    = threadIdx.x;
    const int lane = t & 63;
    const int wv   = t >> 6;          // wave 0..7 owns cols [wv*32, wv*32+32)
    const int l15  = lane & 15;
    const int lg   = lane >> 4;       // 0..3
    const int b0   = blockIdx.x * BT;

    // register double-buffers for the weight stream (K=128 macro-tiles)
    short8 bufA[4][2], bufB[4][2];

    auto loadW = [&](short8 (&dst)[4][2], const unsigned short* wbase, int ldk, int kBase) {
        #pragma unroll
        for (int c = 0; c < 4; ++c)
            #pragma unroll
            for (int n = 0; n < 2; ++n) {
                int col = wv * 32 + n * 16 + l15;
                int kl  = kBase + c * 32 + lg * 8;
                dst[c][n] = *reinterpret_cast<const short8*>(wbase + (size_t)col * ldk + kl);
            }
    };
    auto mfma4_hA = [&](short8 (&bw)[4][2], f32x4 (&acc)[4][2], int kBase) {
        #pragma unroll
        for (int c = 0; c < 4; ++c) {
            int kl = kBase + c * 32 + lg * 8;
            short8 af[4];
            #pragma unroll
            for (int m = 0; m < 4; ++m) {
                int row = m * 16 + l15;
                af[m] = *reinterpret_cast<const short8*>(
                    hA + (row << 10) + (((kl >> 3) ^ (row & 7)) << 4));
            }
            #pragma unroll
            for (int n = 0; n < 2; ++n)
                #pragma unroll
                for (int m = 0; m < 4; ++m)
                    acc[m][n] = __builtin_amdgcn_mfma_f32_16x16x32_bf16(
                        af[m], bw[c][n], acc[m][n], 0, 0, 0);
        }
    };
    auto mfma4_hid = [&](const char* hsrc, short8 (&bw)[4][2], f32x4 (&acc)[4][2], int kBase) {
        #pragma unroll
        for (int c = 0; c < 4; ++c) {
            int kl = kBase + c * 32 + lg * 8;
            short8 af[4];
            #pragma unroll
            for (int m = 0; m < 4; ++m) {
                int row = m * 16 + l15;
                af[m] = *reinterpret_cast<const short8*>(
                    hsrc + (row << 9) + (((kl >> 3) ^ (row & 7)) << 4));
            }
            #pragma unroll
            for (int n = 0; n < 2; ++n)
                #pragma unroll
                for (int m = 0; m < 4; ++m)
                    acc[m][n] = __builtin_amdgcn_mfma_f32_16x16x32_bf16(
                        af[m], bw[c][n], acc[m][n], 0, 0, 0);
        }
    };

    // prefetch expert-0 GEMM1 macro-0 immediately (hides under staging+gating)
    loadW(bufA, w1t, Dd, 0);

    // ---- stage h tile -> bf16 swizzled LDS ----
    {
        const float4* hsrc = reinterpret_cast<const float4*>(hptr + (size_t)b0 * Dd);
        #pragma unroll
        for (int i = 0; i < 16; ++i) {
            int idx = t + i * 512;
            int row = idx >> 7;
            int kc  = idx & 127;
            int k   = kc << 2;
            float4 v = hsrc[(size_t)row * 128 + kc];
            unsigned lo = (unsigned)f2bf(v.x) | ((unsigned)f2bf(v.y) << 16);
            unsigned hi = (unsigned)f2bf(v.z) | ((unsigned)f2bf(v.w) << 16);
            int byte = (row << 10) + (((k >> 3) ^ (row & 7)) << 4) + ((k & 7) << 1);
            *reinterpret_cast<uint2*>(hA + byte) = make_uint2(lo, hi);
        }
    }
    __syncthreads();

    // ---- gating via MFMA: all waves compute 64x16 logits, wave 0 stores ----
    {
        f32x4 g[4];
        #pragma unroll
        for (int m = 0; m < 4; ++m) g[m] = (f32x4){0.f, 0.f, 0.f, 0.f};
        #pragma unroll
        for (int kc = 0; kc < 16; ++kc) {
            int kb = kc * 32 + lg * 8;
            short8 bfr;
            #pragma unroll
            for (int j = 0; j < 8; ++j)
                bfr[j] = (short)f2bf(phi[(size_t)(kb + j) * Ee + l15]);
            #pragma unroll
            for (int m = 0; m < 4; ++m) {
                int row = m * 16 + l15;
                short8 af = *reinterpret_cast<const short8*>(
                    hA + (row << 10) + (((kb >> 3) ^ (row & 7)) << 4));
                g[m] = __builtin_amdgcn_mfma_f32_16x16x32_bf16(af, bfr, g[m], 0, 0, 0);
            }
        }
        if (wv == 0) {
            #pragma unroll
            for (int m = 0; m < 4; ++m)
                #pragma unroll
                for (int j = 0; j < 4; ++j)
                    wc[(m * 16 + lg * 4 + j) * WCLD + l15] = g[m][j];
        }
    }
    __syncthreads();
    if (t < 64) {
        float w[16];
        float mx = -1e30f;
        #pragma unroll
        for (int e = 0; e < 16; ++e) { w[e] = wc[t * WCLD + e]; mx = fmaxf(mx, w[e]); }
        float s = 0.f;
        #pragma unroll
        for (int e = 0; e < 16; ++e) { w[e] = __expf(w[e] - mx); s += w[e]; }
        float inv = 1.f / s;
        #pragma unroll
        for (int e = 0; e < 16; ++e) wc[t * WCLD + e] = w[e] * inv;
    }
    __syncthreads();

    const f32x4 zero4 = {0.f, 0.f, 0.f, 0.f};
    f32x4 outacc[4][2];
    #pragma unroll
    for (int m = 0; m < 4; ++m)
        #pragma unroll
        for (int n = 0; n < 2; ++n) outacc[m][n] = zero4;

    const unsigned short* w1e = w1t;
    for (int e = 0; e < Ee; ++e) {
        const unsigned short* w2e = w2t + (size_t)e * Zz * Hh;
        const unsigned short* w1n = w1t + (size_t)((e + 1) & 15) * Hh * Dd;
        char* hw = (e & 1) ? hidB1 : hidB0;

        f32x4 hacc[4][2];
        #pragma unroll
        for (int m = 0; m < 4; ++m)
            #pragma unroll
            for (int n = 0; n < 2; ++n) hacc[m][n] = zero4;

        // GEMM1: hid = h @ W1[e], K=512 as 4 macro-steps, dbuf prefetch
        loadW(bufB, w1e, Dd, 128);  mfma4_hA(bufA, hacc, 0);
        loadW(bufA, w1e, Dd, 256);  mfma4_hA(bufB, hacc, 128);
        loadW(bufB, w1e, Dd, 384);  mfma4_hA(bufA, hacc, 256);
        loadW(bufA, w2e, Hh, 0);    mfma4_hA(bufB, hacc, 384);   // prefetch GEMM2

        // epilogue1: +b1, relu, * c[row,e] -> bf16 hw (double-buffered)
        #pragma unroll
        for (int n = 0; n < 2; ++n) {
            int col = wv * 32 + n * 16 + l15;
            float bias = b1[(size_t)e * Hh + col];
            #pragma unroll
            for (int m = 0; m < 4; ++m) {
                #pragma unroll
                for (int j = 0; j < 4; ++j) {
                    int row = m * 16 + lg * 4 + j;
                    float v = fmaxf(hacc[m][n][j] + bias, 0.f) * wc[row * WCLD + e];
                    int byte = (row << 9) + (((col >> 3) ^ (row & 7)) << 4) + ((col & 7) << 1);
                    *reinterpret_cast<unsigned short*>(hw + byte) = f2bf(v);
                }
            }
        }
        __syncthreads();   // hw complete before any wave reads it

        // GEMM2: out += hid' @ W2[e], K=256 as 2 macro-steps
        loadW(bufB, w2e, Hh, 128);  mfma4_hid(hw, bufA, outacc, 0);
        loadW(bufA, w1n, Dd, 0);    mfma4_hid(hw, bufB, outacc, 128); // prefetch next e

        w1e = w1n;
    }

    // ---- final epilogue: out = outacc + sum_e c[row,e]*b2[e,:] ----
    float b2v[2][16];
    #pragma unroll
    for (int n = 0; n < 2; ++n) {
        int col = wv * 32 + n * 16 + l15;
        #pragma unroll
        for (int e = 0; e < 16; ++e) b2v[n][e] = b2[(size_t)e * Zz + col];
    }
    #pragma unroll
    for (int m = 0; m < 4; ++m) {
        #pragma unroll
        for (int j = 0; j < 4; ++j) {
            int row = m * 16 + lg * 4 + j;
            float wrow[16];
            #pragma unroll
            for (int e = 0; e < 16; ++e) wrow[e] = wc[row * WCLD + e];
            #pragma unroll
            for (int n = 0; n < 2; ++n) {
                int col = wv * 32 + n * 16 + l15;
                float v = outacc[m][n][j];
                #pragma unroll
                for (int e = 0; e < 16; ++e) v = fmaf(wrow[e], b2v[n][e], v);
                out[(size_t)(b0 + row) * Zz + col] = v;
            }
        }
    }
}

extern "C" void kernel_launch(void* const* d_in, const int* in_sizes, int n_in,
                              void* d_out, int out_size, void* d_ws, size_t ws_size,
                              hipStream_t stream) {
    const float* h   = (const float*)d_in[0];
    const float* phi = (const float*)d_in[1];
    const float* W1  = (const float*)d_in[2];
    const float* b1  = (const float*)d_in[3];
    const float* W2  = (const float*)d_in[4];
    const float* b2  = (const float*)d_in[5];
    float* out = (float*)d_out;

    unsigned short* w1t = (unsigned short*)d_ws;                      // 4 MB
    unsigned short* w2t = w1t + (size_t)Ee * Hh * Dd;                 // 2 MB

    (void)hipFuncSetAttribute((const void*)moe_fused,
                              hipFuncAttributeMaxDynamicSharedMemorySize, SMEM_MAIN);

    transpose_bf16<<<Ee * (Dd / 64) * (Hh / 64), 256, 0, stream>>>(W1, w1t, Dd, Hh);
    transpose_bf16<<<Ee * (Hh / 64) * (Zz / 64), 256, 0, stream>>>(W2, w2t, Hh, Zz);

    moe_fused<<<Bsz / BT, 512, SMEM_MAIN, stream>>>(h, phi, b1, b2, w1t, w2t, out);
}